// Round 2
// baseline (285.321 us; speedup 1.0000x reference)
//
#include <hip/hip_runtime.h>
#include <stdint.h>

typedef uint16_t u16;
typedef __bf16 bf16x8 __attribute__((ext_vector_type(8)));
typedef float f32x4 __attribute__((ext_vector_type(4)));
typedef uint16_t u16x4 __attribute__((ext_vector_type(4)));
typedef uint16_t u16x8 __attribute__((ext_vector_type(8)));

__device__ __forceinline__ float bf2f(u16 b) {
    union { uint32_t u; float f; } v; v.u = ((uint32_t)b) << 16; return v.f;
}
__device__ __forceinline__ u16 f2bf(float f) {
    union { float f; uint32_t u; } v; v.f = f;
    uint32_t u = v.u;
    u += 0x7fffu + ((u >> 16) & 1u);   // RNE
    return (u16)(u >> 16);
}

// ---------------------------------------------------------------------------
// C[M,N] = A[M,K] @ B[N,K]^T (+ bias). A is fp32 or bf16 (A_F32), B/bias fp32,
// C is fp32 or bf16 (C_F32). f32 accumulate via bf16 MFMA. 128x128 tile, BK=32,
// 4 waves (2x2 of 64x64), register staging with fp32->bf16 convert at ds_write.
// grid = (N/128, M/128); all dims divisible.
// ---------------------------------------------------------------------------
template<bool A_F32, bool C_F32>
__global__ __launch_bounds__(256) void gemm_bt(
    const void* __restrict__ Av, int lda,
    const float* __restrict__ B, int ldb,   // [N][K] fp32
    const float* __restrict__ bias,         // [N] fp32 or nullptr
    void* __restrict__ Cv, int ldc,
    int K)
{
    __shared__ u16 lA[128 * 32];
    __shared__ u16 lB[128 * 32];

    const int tid  = threadIdx.x;
    const int lane = tid & 63;
    const int wave = tid >> 6;
    const int wr   = (wave >> 1) * 64;
    const int wc   = (wave & 1) * 64;
    const int row0 = blockIdx.y * 128;
    const int col0 = blockIdx.x * 128;

    f32x4 acc[4][4] = {};

    for (int k0 = 0; k0 < K; k0 += 32) {
        // stage 128x32 A and B tiles: 1024 chunks of 4 elems, 4 iters x 256 thr
        #pragma unroll
        for (int i = 0; i < 4; ++i) {
            const int idx = i * 256 + tid;
            const int r = idx >> 3;
            const int p = (idx & 7) * 4;
            u16x4 a4, b4;
            if constexpr (A_F32) {
                const float* Af = (const float*)Av;
                f32x4 va = *(const f32x4*)(Af + (size_t)(row0 + r) * lda + k0 + p);
                a4[0] = f2bf(va[0]); a4[1] = f2bf(va[1]); a4[2] = f2bf(va[2]); a4[3] = f2bf(va[3]);
            } else {
                const u16* Ab = (const u16*)Av;
                a4 = *(const u16x4*)(Ab + (size_t)(row0 + r) * lda + k0 + p);
            }
            {
                f32x4 vb = *(const f32x4*)(B + (size_t)(col0 + r) * ldb + k0 + p);
                b4[0] = f2bf(vb[0]); b4[1] = f2bf(vb[1]); b4[2] = f2bf(vb[2]); b4[3] = f2bf(vb[3]);
            }
            *(u16x4*)&lA[r * 32 + p] = a4;
            *(u16x4*)&lB[r * 32 + p] = b4;
        }
        __syncthreads();

        bf16x8 af[4], bfv[4];
        #pragma unroll
        for (int m = 0; m < 4; ++m)
            af[m] = *(const bf16x8*)(lA + (wr + m * 16 + (lane & 15)) * 32 + (lane >> 4) * 8);
        #pragma unroll
        for (int n = 0; n < 4; ++n)
            bfv[n] = *(const bf16x8*)(lB + (wc + n * 16 + (lane & 15)) * 32 + (lane >> 4) * 8);
        #pragma unroll
        for (int m = 0; m < 4; ++m)
            #pragma unroll
            for (int n = 0; n < 4; ++n)
                acc[m][n] = __builtin_amdgcn_mfma_f32_16x16x32_bf16(af[m], bfv[n], acc[m][n], 0, 0, 0);
        __syncthreads();
    }

    #pragma unroll
    for (int m = 0; m < 4; ++m) {
        const int r = row0 + wr + m * 16 + ((lane >> 4) << 2);
        #pragma unroll
        for (int n = 0; n < 4; ++n) {
            const int c = col0 + wc + n * 16 + (lane & 15);
            const float bv = bias ? bias[c] : 0.f;
            #pragma unroll
            for (int j = 0; j < 4; ++j) {
                const float val = acc[m][n][j] + bv;
                if constexpr (C_F32) ((float*)Cv)[(size_t)(r + j) * ldc + c] = val;
                else                 ((u16*)Cv)[(size_t)(r + j) * ldc + c] = f2bf(val);
            }
        }
    }
}

// ---------------------------------------------------------------------------
// Local attention. One block per (b, h, window). 256 threads = 4 waves,
// each wave owns 32 q-rows. qkv layout (bf16): [B*N][1536] = [q k v],
// head h at column h*64. Output written into the q-columns (exclusively owned).
// ---------------------------------------------------------------------------
__global__ __launch_bounds__(256) void attn_kernel(const u16* qkv, u16* o)
{
    constexpr int CC = 1536;
    constexpr int NTOK = 8192;
    constexpr int KP = 72;    // kn pitch (u16), 144B rows (16B-aligned)
    constexpr int VP = 264;   // vT pitch, 528B rows
    constexpr int PP = 264;   // P pitch
    __shared__ u16 kn[256 * KP];   // normalized K window  [key][d]
    __shared__ u16 vT[64 * VP];    // V window transposed  [d][key]
    __shared__ u16 Pl[128 * PP];   // attn probs           [row][key]

    const int tid  = threadIdx.x;
    const int lane = tid & 63;
    const int wave = tid >> 6;

    const int blk = blockIdx.x;
    const int iw  = blk & 63;          // window index (nw=64)
    const int h   = (blk >> 6) & 7;
    const int b   = blk >> 9;

    const int tq0 = iw * 128;
    const int tk0 = iw * 128 - 128;    // key j -> token tk0+j, j in [0,256)
    const size_t rowbase = (size_t)b * NTOK;
    const u16* qbase = qkv + rowbase * CC + h * 64;
    const u16* kbase = qbase + 512;
    const u16* vbase = qbase + 1024;

    // ---- stage L2-normalized K ----
    {
        const int c = tid & 3;             // 16-elem chunk within row
        int key = tid >> 2;                // 0..63, +64 per pass
        for (int pass = 0; pass < 4; ++pass, key += 64) {
            const int tk = tk0 + key;
            float vals[16];
            if (tk >= 0) {
                const u16* g = kbase + (size_t)tk * CC + c * 16;
                u16x8 v0 = *(const u16x8*)g;
                u16x8 v1 = *(const u16x8*)(g + 8);
                #pragma unroll
                for (int e = 0; e < 8; ++e) { vals[e] = bf2f(v0[e]); vals[8 + e] = bf2f(v1[e]); }
            } else {
                #pragma unroll
                for (int e = 0; e < 16; ++e) vals[e] = 0.f;
            }
            float ss = 0.f;
            #pragma unroll
            for (int e = 0; e < 16; ++e) ss += vals[e] * vals[e];
            ss += __shfl_xor(ss, 1);
            ss += __shfl_xor(ss, 2);
            const float scl = 1.f / fmaxf(sqrtf(ss), 1e-12f);
            u16x8 w0, w1;
            #pragma unroll
            for (int e = 0; e < 8; ++e) { w0[e] = f2bf(vals[e] * scl); w1[e] = f2bf(vals[8 + e] * scl); }
            *(u16x8*)&kn[key * KP + c * 16]     = w0;
            *(u16x8*)&kn[key * KP + c * 16 + 8] = w1;
        }
    }

    // ---- stage V transposed ----
    {
        const int d = tid & 63;
        const int g = tid >> 6;            // key block of 64
        #pragma unroll
        for (int c8 = 0; c8 < 8; ++c8) {
            const int key0 = g * 64 + c8 * 8;
            u16x8 vv;
            #pragma unroll
            for (int e = 0; e < 8; ++e) {
                const int tk = tk0 + key0 + e;
                vv[e] = (tk >= 0) ? vbase[(size_t)tk * CC + d] : (u16)0;
            }
            *(u16x8*)&vT[d * VP + key0] = vv;
        }
    }
    __syncthreads();

    // ---- Q fragments (each wave reads only its own 32 rows) ----
    const int wrow = wave * 32;
    bf16x8 qf[2][2];
    #pragma unroll
    for (int m = 0; m < 2; ++m)
        #pragma unroll
        for (int kk = 0; kk < 2; ++kk) {
            const int r = tq0 + wrow + m * 16 + (lane & 15);
            qf[m][kk] = *(const bf16x8*)(qbase + (size_t)r * CC + kk * 32 + (lane >> 4) * 8);
        }

    // ---- S = Q @ Kn^T  (wave: 32 rows x 256 keys) ----
    f32x4 sacc[2][16] = {};
    #pragma unroll
    for (int n = 0; n < 16; ++n) {
        #pragma unroll
        for (int kk = 0; kk < 2; ++kk) {
            const bf16x8 kf = *(const bf16x8*)&kn[(n * 16 + (lane & 15)) * KP + kk * 32 + (lane >> 4) * 8];
            #pragma unroll
            for (int m = 0; m < 2; ++m)
                sacc[m][n] = __builtin_amdgcn_mfma_f32_16x16x32_bf16(qf[m][kk], kf, sacc[m][n], 0, 0, 0);
        }
    }

    // ---- mask + softmax (in-register; C layout: col=lane&15, row=(lane>>4)*4+j) ----
    const int cl = lane & 15;
    const int gr = lane >> 4;
    #pragma unroll
    for (int m = 0; m < 2; ++m) {
        const int rloc = wrow + m * 16 + gr * 4;   // + j
        float mx[4] = {-3.4e38f, -3.4e38f, -3.4e38f, -3.4e38f};
        #pragma unroll
        for (int n = 0; n < 16; ++n) {
            const int jj = n * 16 + cl;
            const int tkk = tk0 + jj;
            const bool pad = tkk < 0;
            #pragma unroll
            for (int j = 0; j < 4; ++j) {
                const int tq = tq0 + rloc + j;
                float s = sacc[m][n][j] * 0.125f;          // D^-0.5
                const int rel = tkk - tq;
                s = (rel == 0) ? -5.0e4f : s;              // shared_qk self mask
                s = (rel > 0 || pad) ? -6.0e4f : s;        // causal / pad (underflows to 0 in softmax)
                sacc[m][n][j] = s;
                mx[j] = fmaxf(mx[j], s);
            }
        }
        #pragma unroll
        for (int j = 0; j < 4; ++j) {
            mx[j] = fmaxf(mx[j], __shfl_xor(mx[j], 1));
            mx[j] = fmaxf(mx[j], __shfl_xor(mx[j], 2));
            mx[j] = fmaxf(mx[j], __shfl_xor(mx[j], 4));
            mx[j] = fmaxf(mx[j], __shfl_xor(mx[j], 8));
        }
        float sm[4] = {0.f, 0.f, 0.f, 0.f};
        #pragma unroll
        for (int n = 0; n < 16; ++n)
            #pragma unroll
            for (int j = 0; j < 4; ++j) {
                const float p = __expf(sacc[m][n][j] - mx[j]);
                sacc[m][n][j] = p;
                sm[j] += p;
            }
        #pragma unroll
        for (int j = 0; j < 4; ++j) {
            sm[j] += __shfl_xor(sm[j], 1);
            sm[j] += __shfl_xor(sm[j], 2);
            sm[j] += __shfl_xor(sm[j], 4);
            sm[j] += __shfl_xor(sm[j], 8);
            sm[j] = 1.f / sm[j];
        }
        #pragma unroll
        for (int n = 0; n < 16; ++n) {
            const int jj = n * 16 + cl;
            #pragma unroll
            for (int j = 0; j < 4; ++j)
                Pl[(rloc + j) * PP + jj] = f2bf(sacc[m][n][j] * sm[j]);
        }
    }
    __syncthreads();

    // ---- O = P @ V ----
    f32x4 oacc[2][4] = {};
    #pragma unroll
    for (int kk = 0; kk < 8; ++kk) {
        bf16x8 pa[2];
        #pragma unroll
        for (int m = 0; m < 2; ++m)
            pa[m] = *(const bf16x8*)&Pl[(wrow + m * 16 + cl) * PP + kk * 32 + gr * 8];
        #pragma unroll
        for (int n = 0; n < 4; ++n) {
            const bf16x8 vb = *(const bf16x8*)&vT[(n * 16 + cl) * VP + kk * 32 + gr * 8];
            #pragma unroll
            for (int m = 0; m < 2; ++m)
                oacc[m][n] = __builtin_amdgcn_mfma_f32_16x16x32_bf16(pa[m], vb, oacc[m][n], 0, 0, 0);
        }
    }

    // ---- write O into the q-columns (exclusively owned by this block) ----
    u16* obase = o + rowbase * CC + h * 64;
    #pragma unroll
    for (int m = 0; m < 2; ++m) {
        const int r0 = tq0 + wrow + m * 16 + gr * 4;
        #pragma unroll
        for (int n = 0; n < 4; ++n) {
            const int d = n * 16 + cl;
            #pragma unroll
            for (int j = 0; j < 4; ++j)
                obase[(size_t)(r0 + j) * CC + d] = f2bf(oacc[m][n][j]);
        }
    }
}

extern "C" void kernel_launch(void* const* d_in, const int* in_sizes, int n_in,
                              void* d_out, int out_size, void* d_ws, size_t ws_size,
                              hipStream_t stream)
{
    (void)in_sizes; (void)n_in; (void)out_size; (void)ws_size;
    const float* x      = (const float*)d_in[0];   // [4,8192,512] fp32
    const float* w_qkv  = (const float*)d_in[1];   // [1536,512]   fp32
    const float* w_proj = (const float*)d_in[2];   // [512,512]    fp32
    const float* b_proj = (const float*)d_in[3];   // [512]        fp32
    float* out = (float*)d_out;                    // [4,8192,512] fp32
    u16* qkv = (u16*)d_ws;                         // [32768][1536] bf16 = 96 MiB

    const int BN = 4 * 8192;
    dim3 blk(256);
    // qkv(bf16) = x @ w_qkv^T
    gemm_bt<true, false><<<dim3(1536 / 128, BN / 128), blk, 0, stream>>>(
        x, 512, w_qkv, 512, nullptr, qkv, 1536, 512);
    // local attention; O (bf16) overwrites q-columns of qkv
    attn_kernel<<<dim3(4 * 8 * 64), blk, 0, stream>>>(qkv, qkv);
    // out(fp32) = attnO @ w_proj^T + b_proj   (A = q-columns, lda=1536)
    gemm_bt<false, true><<<dim3(512 / 128, BN / 128), blk, 0, stream>>>(
        qkv, 1536, w_proj, 512, b_proj, out, 512, 512);
}

// Round 3
// 234.426 us; speedup vs baseline: 1.2171x; 1.2171x over previous
//
#include <hip/hip_runtime.h>
#include <stdint.h>

typedef uint16_t u16;
typedef __bf16 bf16x8 __attribute__((ext_vector_type(8)));
typedef float f32x4 __attribute__((ext_vector_type(4)));
typedef uint16_t u16x4 __attribute__((ext_vector_type(4)));
typedef uint16_t u16x8 __attribute__((ext_vector_type(8)));

typedef __attribute__((address_space(1))) void as1_void;
typedef __attribute__((address_space(3))) void as3_void;

__device__ __forceinline__ float bf2f(u16 b) {
    union { uint32_t u; float f; } v; v.u = ((uint32_t)b) << 16; return v.f;
}
__device__ __forceinline__ u16 f2bf(float f) {
    union { float f; uint32_t u; } v; v.f = f;
    uint32_t u = v.u;
    u += 0x7fffu + ((u >> 16) & 1u);   // RNE
    return (u16)(u >> 16);
}
__device__ __forceinline__ void gload_lds16(const u16* g, u16* l) {
    __builtin_amdgcn_global_load_lds((as1_void*)g, (as3_void*)l, 16, 0, 0);
}

// ---------------------------------------------------------------------------
// fp32 -> bf16 bulk convert (n multiple of 8), grid-stride, 16B loads.
// ---------------------------------------------------------------------------
__global__ __launch_bounds__(256) void cvt_f32_bf16(const float* __restrict__ in,
                                                    u16* __restrict__ out, int n)
{
    int i = (blockIdx.x * 256 + threadIdx.x) * 8;
    const int stride = gridDim.x * 256 * 8;
    for (; i < n; i += stride) {
        f32x4 a = *(const f32x4*)(in + i);
        f32x4 b = *(const f32x4*)(in + i + 4);
        u16x8 o;
        o[0] = f2bf(a[0]); o[1] = f2bf(a[1]); o[2] = f2bf(a[2]); o[3] = f2bf(a[3]);
        o[4] = f2bf(b[0]); o[5] = f2bf(b[1]); o[6] = f2bf(b[2]); o[7] = f2bf(b[3]);
        *(u16x8*)(out + i) = o;
    }
}

// ---------------------------------------------------------------------------
// bf16 GEMM, m97 structure: C[M,N] = A[M,K] @ B[N,K]^T (+ fp32 bias).
// 128x128 tile, BK=32, 4 waves, global_load_lds width-16 staging.
// ---------------------------------------------------------------------------
template<bool C_F32>
__global__ __launch_bounds__(256) void gemm_bt_bf16(
    const u16* __restrict__ A, int lda,
    const u16* __restrict__ B, int ldb,
    const float* __restrict__ bias,
    void* __restrict__ Cv, int ldc,
    int K)
{
    __shared__ u16 lA[128 * 32];
    __shared__ u16 lB[128 * 32];

    const int tid  = threadIdx.x;
    const int lane = tid & 63;
    const int wave = tid >> 6;
    const int wr   = (wave >> 1) * 64;
    const int wc   = (wave & 1) * 64;
    const int row0 = blockIdx.y * 128;
    const int col0 = blockIdx.x * 128;

    f32x4 acc[4][4] = {};

    for (int k0 = 0; k0 < K; k0 += 32) {
        #pragma unroll
        for (int i = 0; i < 2; ++i) {
            const int idx = i * 256 + tid;   // 16B chunk: row=idx>>2, sub=idx&3
            gload_lds16(A + (size_t)(row0 + (idx >> 2)) * lda + k0 + (idx & 3) * 8,
                        lA + (size_t)(i * 256 + wave * 64) * 8);
            gload_lds16(B + (size_t)(col0 + (idx >> 2)) * ldb + k0 + (idx & 3) * 8,
                        lB + (size_t)(i * 256 + wave * 64) * 8);
        }
        __syncthreads();

        bf16x8 af[4], bfv[4];
        #pragma unroll
        for (int m = 0; m < 4; ++m)
            af[m] = *(const bf16x8*)(lA + (wr + m * 16 + (lane & 15)) * 32 + (lane >> 4) * 8);
        #pragma unroll
        for (int n = 0; n < 4; ++n)
            bfv[n] = *(const bf16x8*)(lB + (wc + n * 16 + (lane & 15)) * 32 + (lane >> 4) * 8);
        #pragma unroll
        for (int m = 0; m < 4; ++m)
            #pragma unroll
            for (int n = 0; n < 4; ++n)
                acc[m][n] = __builtin_amdgcn_mfma_f32_16x16x32_bf16(af[m], bfv[n], acc[m][n], 0, 0, 0);
        __syncthreads();
    }

    #pragma unroll
    for (int m = 0; m < 4; ++m) {
        const int r = row0 + wr + m * 16 + ((lane >> 4) << 2);
        #pragma unroll
        for (int n = 0; n < 4; ++n) {
            const int c = col0 + wc + n * 16 + (lane & 15);
            const float bv = bias ? bias[c] : 0.f;
            #pragma unroll
            for (int j = 0; j < 4; ++j) {
                const float val = acc[m][n][j] + bv;
                if constexpr (C_F32) ((float*)Cv)[(size_t)(r + j) * ldc + c] = val;
                else                 ((u16*)Cv)[(size_t)(r + j) * ldc + c] = f2bf(val);
            }
        }
    }
}

// ---------------------------------------------------------------------------
// fp32-input fallback GEMM (register staging + convert). Used only if ws too small.
// ---------------------------------------------------------------------------
template<bool A_F32, bool C_F32>
__global__ __launch_bounds__(256) void gemm_bt_f32(
    const void* __restrict__ Av, int lda,
    const float* __restrict__ B, int ldb,
    const float* __restrict__ bias,
    void* __restrict__ Cv, int ldc,
    int K)
{
    __shared__ u16 lA[128 * 32];
    __shared__ u16 lB[128 * 32];

    const int tid  = threadIdx.x;
    const int lane = tid & 63;
    const int wave = tid >> 6;
    const int wr   = (wave >> 1) * 64;
    const int wc   = (wave & 1) * 64;
    const int row0 = blockIdx.y * 128;
    const int col0 = blockIdx.x * 128;

    f32x4 acc[4][4] = {};

    for (int k0 = 0; k0 < K; k0 += 32) {
        #pragma unroll
        for (int i = 0; i < 4; ++i) {
            const int idx = i * 256 + tid;
            const int r = idx >> 3;
            const int p = (idx & 7) * 4;
            u16x4 a4, b4;
            if constexpr (A_F32) {
                const float* Af = (const float*)Av;
                f32x4 va = *(const f32x4*)(Af + (size_t)(row0 + r) * lda + k0 + p);
                a4[0] = f2bf(va[0]); a4[1] = f2bf(va[1]); a4[2] = f2bf(va[2]); a4[3] = f2bf(va[3]);
            } else {
                const u16* Ab = (const u16*)Av;
                a4 = *(const u16x4*)(Ab + (size_t)(row0 + r) * lda + k0 + p);
            }
            {
                f32x4 vb = *(const f32x4*)(B + (size_t)(col0 + r) * ldb + k0 + p);
                b4[0] = f2bf(vb[0]); b4[1] = f2bf(vb[1]); b4[2] = f2bf(vb[2]); b4[3] = f2bf(vb[3]);
            }
            *(u16x4*)&lA[r * 32 + p] = a4;
            *(u16x4*)&lB[r * 32 + p] = b4;
        }
        __syncthreads();

        bf16x8 af[4], bfv[4];
        #pragma unroll
        for (int m = 0; m < 4; ++m)
            af[m] = *(const bf16x8*)(lA + (wr + m * 16 + (lane & 15)) * 32 + (lane >> 4) * 8);
        #pragma unroll
        for (int n = 0; n < 4; ++n)
            bfv[n] = *(const bf16x8*)(lB + (wc + n * 16 + (lane & 15)) * 32 + (lane >> 4) * 8);
        #pragma unroll
        for (int m = 0; m < 4; ++m)
            #pragma unroll
            for (int n = 0; n < 4; ++n)
                acc[m][n] = __builtin_amdgcn_mfma_f32_16x16x32_bf16(af[m], bfv[n], acc[m][n], 0, 0, 0);
        __syncthreads();
    }

    #pragma unroll
    for (int m = 0; m < 4; ++m) {
        const int r = row0 + wr + m * 16 + ((lane >> 4) << 2);
        #pragma unroll
        for (int n = 0; n < 4; ++n) {
            const int c = col0 + wc + n * 16 + (lane & 15);
            const float bv = bias ? bias[c] : 0.f;
            #pragma unroll
            for (int j = 0; j < 4; ++j) {
                const float val = acc[m][n][j] + bv;
                if constexpr (C_F32) ((float*)Cv)[(size_t)(r + j) * ldc + c] = val;
                else                 ((u16*)Cv)[(size_t)(r + j) * ldc + c] = f2bf(val);
            }
        }
    }
}

// ---------------------------------------------------------------------------
// Local attention. One block per (b, h, window). 512 threads = 8 waves,
// each wave owns 16 q-rows (2 waves/SIMD for latency hiding at 135KB LDS).
// qkv (bf16): [B*N][1536] = [q k v], head h at column h*64.
// Output written into the q-columns (exclusively owned by this block).
// ---------------------------------------------------------------------------
__global__ __launch_bounds__(512) void attn_kernel(const u16* qkv, u16* o)
{
    constexpr int CC = 1536;
    constexpr int NTOK = 8192;
    constexpr int KP = 72;    // kn pitch (u16), 144B rows (16B-aligned, bank-skewed)
    constexpr int VP = 264;   // vT pitch
    constexpr int PP = 264;   // P pitch
    __shared__ u16 kn[256 * KP];   // normalized K window  [key][d]
    __shared__ u16 vT[64 * VP];    // V window transposed  [d][key]
    __shared__ u16 Pl[128 * PP];   // attn probs           [row][key]

    const int tid  = threadIdx.x;
    const int lane = tid & 63;
    const int wave = tid >> 6;

    const int blk = blockIdx.x;
    const int iw  = blk & 63;          // window index (nw=64)
    const int h   = (blk >> 6) & 7;
    const int b   = blk >> 9;

    const int tq0 = iw * 128;
    const int tk0 = iw * 128 - 128;    // key j -> token tk0+j, j in [0,256)
    const size_t rowbase = (size_t)b * NTOK;
    const u16* qbase = qkv + rowbase * CC + h * 64;
    const u16* kbase = qbase + 512;
    const u16* vbase = qbase + 1024;

    // ---- stage L2-normalized K (512 thr: 128 keys/pass, 2 passes) ----
    {
        const int c = tid & 3;             // 16-elem chunk within row
        int key = tid >> 2;                // 0..127, +128 second pass
        #pragma unroll
        for (int pass = 0; pass < 2; ++pass, key += 128) {
            const int tk = tk0 + key;
            float vals[16];
            if (tk >= 0) {
                const u16* g = kbase + (size_t)tk * CC + c * 16;
                u16x8 v0 = *(const u16x8*)g;
                u16x8 v1 = *(const u16x8*)(g + 8);
                #pragma unroll
                for (int e = 0; e < 8; ++e) { vals[e] = bf2f(v0[e]); vals[8 + e] = bf2f(v1[e]); }
            } else {
                #pragma unroll
                for (int e = 0; e < 16; ++e) vals[e] = 0.f;
            }
            float ss = 0.f;
            #pragma unroll
            for (int e = 0; e < 16; ++e) ss += vals[e] * vals[e];
            ss += __shfl_xor(ss, 1);
            ss += __shfl_xor(ss, 2);
            const float scl = 1.f / fmaxf(sqrtf(ss), 1e-12f);
            u16x8 w0, w1;
            #pragma unroll
            for (int e = 0; e < 8; ++e) { w0[e] = f2bf(vals[e] * scl); w1[e] = f2bf(vals[8 + e] * scl); }
            *(u16x8*)&kn[key * KP + c * 16]     = w0;
            *(u16x8*)&kn[key * KP + c * 16 + 8] = w1;
        }
    }

    // ---- stage V transposed (8 key-groups of 32) ----
    {
        const int d = tid & 63;
        const int g = tid >> 6;
        #pragma unroll
        for (int c8 = 0; c8 < 4; ++c8) {
            const int key0 = g * 32 + c8 * 8;
            u16x8 vv;
            #pragma unroll
            for (int e = 0; e < 8; ++e) {
                const int tk = tk0 + key0 + e;
                vv[e] = (tk >= 0) ? vbase[(size_t)tk * CC + d] : (u16)0;
            }
            *(u16x8*)&vT[d * VP + key0] = vv;
        }
    }
    __syncthreads();

    // ---- Q fragments (wave reads only its own 16 rows) ----
    const int wrow = wave * 16;
    bf16x8 qf[2];
    #pragma unroll
    for (int kk = 0; kk < 2; ++kk) {
        const int r = tq0 + wrow + (lane & 15);
        qf[kk] = *(const bf16x8*)(qbase + (size_t)r * CC + kk * 32 + (lane >> 4) * 8);
    }

    // ---- S = Q @ Kn^T  (wave: 16 rows x 256 keys) ----
    f32x4 sacc[16] = {};
    #pragma unroll
    for (int n = 0; n < 16; ++n) {
        #pragma unroll
        for (int kk = 0; kk < 2; ++kk) {
            const bf16x8 kf = *(const bf16x8*)&kn[(n * 16 + (lane & 15)) * KP + kk * 32 + (lane >> 4) * 8];
            sacc[n] = __builtin_amdgcn_mfma_f32_16x16x32_bf16(qf[kk], kf, sacc[n], 0, 0, 0);
        }
    }

    // ---- mask + softmax (in-register; C layout: col=lane&15, row=(lane>>4)*4+j) ----
    const int cl = lane & 15;
    const int gr = lane >> 4;
    {
        const int rloc = wrow + gr * 4;   // + j
        float mx[4] = {-3.4e38f, -3.4e38f, -3.4e38f, -3.4e38f};
        #pragma unroll
        for (int n = 0; n < 16; ++n) {
            const int jj = n * 16 + cl;
            const int tkk = tk0 + jj;
            const bool pad = tkk < 0;
            #pragma unroll
            for (int j = 0; j < 4; ++j) {
                const int tq = tq0 + rloc + j;
                float s = sacc[n][j] * 0.125f;             // D^-0.5
                const int rel = tkk - tq;
                s = (rel == 0) ? -5.0e4f : s;              // shared_qk self mask
                s = (rel > 0 || pad) ? -6.0e4f : s;        // causal / pad
                sacc[n][j] = s;
                mx[j] = fmaxf(mx[j], s);
            }
        }
        #pragma unroll
        for (int j = 0; j < 4; ++j) {
            mx[j] = fmaxf(mx[j], __shfl_xor(mx[j], 1));
            mx[j] = fmaxf(mx[j], __shfl_xor(mx[j], 2));
            mx[j] = fmaxf(mx[j], __shfl_xor(mx[j], 4));
            mx[j] = fmaxf(mx[j], __shfl_xor(mx[j], 8));
        }
        float sm[4] = {0.f, 0.f, 0.f, 0.f};
        #pragma unroll
        for (int n = 0; n < 16; ++n)
            #pragma unroll
            for (int j = 0; j < 4; ++j) {
                const float p = __expf(sacc[n][j] - mx[j]);
                sacc[n][j] = p;
                sm[j] += p;
            }
        #pragma unroll
        for (int j = 0; j < 4; ++j) {
            sm[j] += __shfl_xor(sm[j], 1);
            sm[j] += __shfl_xor(sm[j], 2);
            sm[j] += __shfl_xor(sm[j], 4);
            sm[j] += __shfl_xor(sm[j], 8);
            sm[j] = 1.f / sm[j];
        }
        #pragma unroll
        for (int n = 0; n < 16; ++n) {
            const int jj = n * 16 + cl;
            #pragma unroll
            for (int j = 0; j < 4; ++j)
                Pl[(rloc + j) * PP + jj] = f2bf(sacc[n][j] * sm[j]);
        }
    }
    __syncthreads();

    // ---- O = P @ V ----
    f32x4 oacc[4] = {};
    #pragma unroll
    for (int kk = 0; kk < 8; ++kk) {
        const bf16x8 pa = *(const bf16x8*)&Pl[(wrow + cl) * PP + kk * 32 + gr * 8];
        #pragma unroll
        for (int n = 0; n < 4; ++n) {
            const bf16x8 vb = *(const bf16x8*)&vT[(n * 16 + cl) * VP + kk * 32 + gr * 8];
            oacc[n] = __builtin_amdgcn_mfma_f32_16x16x32_bf16(pa, vb, oacc[n], 0, 0, 0);
        }
    }

    // ---- write O into the q-columns ----
    u16* obase = o + rowbase * CC + h * 64;
    {
        const int r0 = tq0 + wrow + gr * 4;
        #pragma unroll
        for (int n = 0; n < 4; ++n) {
            const int d = n * 16 + cl;
            #pragma unroll
            for (int j = 0; j < 4; ++j)
                obase[(size_t)(r0 + j) * CC + d] = f2bf(oacc[n][j]);
        }
    }
}

extern "C" void kernel_launch(void* const* d_in, const int* in_sizes, int n_in,
                              void* d_out, int out_size, void* d_ws, size_t ws_size,
                              hipStream_t stream)
{
    (void)in_sizes; (void)n_in; (void)out_size;
    const float* x      = (const float*)d_in[0];   // [4,8192,512] fp32
    const float* w_qkv  = (const float*)d_in[1];   // [1536,512]   fp32
    const float* w_proj = (const float*)d_in[2];   // [512,512]    fp32
    const float* b_proj = (const float*)d_in[3];   // [512]        fp32
    float* out = (float*)d_out;                    // [4,8192,512] fp32

    const int BN = 4 * 8192;                       // 32768 rows
    const size_t qkv_b = (size_t)BN * 1536 * 2;    // 96 MiB
    const size_t xb_b  = (size_t)BN * 512 * 2;     // 32 MiB
    const size_t wq_b  = (size_t)1536 * 512 * 2;
    const size_t wp_b  = (size_t)512 * 512 * 2;

    uint8_t* p = (uint8_t*)d_ws;
    u16* qkv = (u16*)p;

    if (ws_size >= qkv_b + xb_b + wq_b + wp_b) {
        u16* xb  = (u16*)(p + qkv_b);
        u16* wqb = (u16*)(p + qkv_b + xb_b);
        u16* wpb = (u16*)(p + qkv_b + xb_b + wq_b);
        cvt_f32_bf16<<<1024, 256, 0, stream>>>(x, xb, BN * 512);
        cvt_f32_bf16<<<96, 256, 0, stream>>>(w_qkv, wqb, 1536 * 512);
        cvt_f32_bf16<<<32, 256, 0, stream>>>(w_proj, wpb, 512 * 512);
        // qkv(bf16) = x @ w_qkv^T   (m97 global_load_lds path)
        gemm_bt_bf16<false><<<dim3(12, BN / 128), 256, 0, stream>>>(
            xb, 512, wqb, 512, nullptr, qkv, 1536, 512);
        attn_kernel<<<dim3(4 * 8 * 64), 512, 0, stream>>>(qkv, qkv);
        gemm_bt_bf16<true><<<dim3(4, BN / 128), 256, 0, stream>>>(
            qkv, 1536, wpb, 512, b_proj, out, 512, 512);
    } else {
        // fallback: fp32 register-staged path (round-2 verified)
        gemm_bt_f32<true, false><<<dim3(12, BN / 128), 256, 0, stream>>>(
            x, 512, w_qkv, 512, nullptr, qkv, 1536, 512);
        attn_kernel<<<dim3(4 * 8 * 64), 512, 0, stream>>>(qkv, qkv);
        gemm_bt_f32<false, true><<<dim3(4, BN / 128), 256, 0, stream>>>(
            qkv, 1536, w_proj, 512, b_proj, out, 512, 512);
    }
}

// Round 4
// 200.867 us; speedup vs baseline: 1.4204x; 1.1671x over previous
//
#include <hip/hip_runtime.h>
#include <stdint.h>

typedef uint16_t u16;
typedef __bf16 bf16x8 __attribute__((ext_vector_type(8)));
typedef float f32x4 __attribute__((ext_vector_type(4)));
typedef uint16_t u16x4 __attribute__((ext_vector_type(4)));
typedef uint16_t u16x8 __attribute__((ext_vector_type(8)));

typedef __attribute__((address_space(1))) void as1_void;
typedef __attribute__((address_space(3))) void as3_void;

__device__ __forceinline__ float bf2f(u16 b) {
    union { uint32_t u; float f; } v; v.u = ((uint32_t)b) << 16; return v.f;
}
__device__ __forceinline__ u16 f2bf(float f) {
    union { float f; uint32_t u; } v; v.f = f;
    uint32_t u = v.u;
    u += 0x7fffu + ((u >> 16) & 1u);   // RNE
    return (u16)(u >> 16);
}
__device__ __forceinline__ void gload_lds16(const u16* g, u16* l) {
    __builtin_amdgcn_global_load_lds((as1_void*)g, (as3_void*)l, 16, 0, 0);
}

// ---------------------------------------------------------------------------
// fp32 -> bf16 bulk convert (n multiple of 8), grid-stride, 16B loads.
// ---------------------------------------------------------------------------
__global__ __launch_bounds__(256) void cvt_f32_bf16(const float* __restrict__ in,
                                                    u16* __restrict__ out, int n)
{
    int i = (blockIdx.x * 256 + threadIdx.x) * 8;
    const int stride = gridDim.x * 256 * 8;
    for (; i < n; i += stride) {
        f32x4 a = *(const f32x4*)(in + i);
        f32x4 b = *(const f32x4*)(in + i + 4);
        u16x8 o;
        o[0] = f2bf(a[0]); o[1] = f2bf(a[1]); o[2] = f2bf(a[2]); o[3] = f2bf(a[3]);
        o[4] = f2bf(b[0]); o[5] = f2bf(b[1]); o[6] = f2bf(b[2]); o[7] = f2bf(b[3]);
        *(u16x8*)(out + i) = o;
    }
}

// ---------------------------------------------------------------------------
// bf16 GEMM, m97 structure + XCD chunked swizzle. C = A @ B^T (+bias).
// NORMK: L2-normalize each 64-col head for output cols in [512,1024)
// (the k-section of the fused qkv output).
// ---------------------------------------------------------------------------
template<bool C_F32, bool NORMK>
__global__ __launch_bounds__(256) void gemm_bt_bf16(
    const u16* __restrict__ A, int lda,
    const u16* __restrict__ B, int ldb,
    const float* __restrict__ bias,
    void* __restrict__ Cv, int ldc,
    int K)
{
    __shared__ u16 lA[128 * 32];
    __shared__ u16 lB[128 * 32];

    const int tid  = threadIdx.x;
    const int lane = tid & 63;
    const int wave = tid >> 6;
    const int wr   = (wave >> 1) * 64;
    const int wc   = (wave & 1) * 64;

    // XCD chunked swizzle (bijective when nwg % 8 == 0)
    int fid = blockIdx.y * gridDim.x + blockIdx.x;
    const int nwg = gridDim.x * gridDim.y;
    if ((nwg & 7) == 0) fid = (fid & 7) * (nwg >> 3) + (fid >> 3);
    const int bx = fid % gridDim.x;
    const int by = fid / gridDim.x;
    const int row0 = by * 128;
    const int col0 = bx * 128;

    f32x4 acc[4][4] = {};

    for (int k0 = 0; k0 < K; k0 += 32) {
        #pragma unroll
        for (int i = 0; i < 2; ++i) {
            const int idx = i * 256 + tid;   // 16B chunk: row=idx>>2, sub=idx&3
            gload_lds16(A + (size_t)(row0 + (idx >> 2)) * lda + k0 + (idx & 3) * 8,
                        lA + (size_t)(i * 256 + wave * 64) * 8);
            gload_lds16(B + (size_t)(col0 + (idx >> 2)) * ldb + k0 + (idx & 3) * 8,
                        lB + (size_t)(i * 256 + wave * 64) * 8);
        }
        __syncthreads();

        bf16x8 af[4], bfv[4];
        #pragma unroll
        for (int m = 0; m < 4; ++m)
            af[m] = *(const bf16x8*)(lA + (wr + m * 16 + (lane & 15)) * 32 + (lane >> 4) * 8);
        #pragma unroll
        for (int n = 0; n < 4; ++n)
            bfv[n] = *(const bf16x8*)(lB + (wc + n * 16 + (lane & 15)) * 32 + (lane >> 4) * 8);
        #pragma unroll
        for (int m = 0; m < 4; ++m)
            #pragma unroll
            for (int n = 0; n < 4; ++n)
                acc[m][n] = __builtin_amdgcn_mfma_f32_16x16x32_bf16(af[m], bfv[n], acc[m][n], 0, 0, 0);
        __syncthreads();
    }

    if constexpr (NORMK) {
        // wave's 64 cols = one head when col0 in k-range; L2-normalize rows
        if (col0 >= 512 && col0 < 1024) {
            #pragma unroll
            for (int m = 0; m < 4; ++m)
                #pragma unroll
                for (int j = 0; j < 4; ++j) {
                    float ss = 0.f;
                    #pragma unroll
                    for (int n = 0; n < 4; ++n) ss += acc[m][n][j] * acc[m][n][j];
                    ss += __shfl_xor(ss, 1);
                    ss += __shfl_xor(ss, 2);
                    ss += __shfl_xor(ss, 4);
                    ss += __shfl_xor(ss, 8);
                    const float scl = 1.f / fmaxf(sqrtf(ss), 1e-12f);
                    #pragma unroll
                    for (int n = 0; n < 4; ++n) acc[m][n][j] *= scl;
                }
        }
    }

    #pragma unroll
    for (int m = 0; m < 4; ++m) {
        const int r = row0 + wr + m * 16 + ((lane >> 4) << 2);
        #pragma unroll
        for (int n = 0; n < 4; ++n) {
            const int c = col0 + wc + n * 16 + (lane & 15);
            const float bv = bias ? bias[c] : 0.f;
            #pragma unroll
            for (int j = 0; j < 4; ++j) {
                const float val = acc[m][n][j] + bv;
                if constexpr (C_F32) ((float*)Cv)[(size_t)(r + j) * ldc + c] = val;
                else                 ((u16*)Cv)[(size_t)(r + j) * ldc + c] = f2bf(val);
            }
        }
    }
}

// ---------------------------------------------------------------------------
// fp32-input fallback GEMM (register staging + convert). Used only if ws too small.
// ---------------------------------------------------------------------------
template<bool A_F32, bool C_F32, bool NORMK>
__global__ __launch_bounds__(256) void gemm_bt_f32(
    const void* __restrict__ Av, int lda,
    const float* __restrict__ B, int ldb,
    const float* __restrict__ bias,
    void* __restrict__ Cv, int ldc,
    int K)
{
    __shared__ u16 lA[128 * 32];
    __shared__ u16 lB[128 * 32];

    const int tid  = threadIdx.x;
    const int lane = tid & 63;
    const int wave = tid >> 6;
    const int wr   = (wave >> 1) * 64;
    const int wc   = (wave & 1) * 64;
    const int row0 = blockIdx.y * 128;
    const int col0 = blockIdx.x * 128;

    f32x4 acc[4][4] = {};

    for (int k0 = 0; k0 < K; k0 += 32) {
        #pragma unroll
        for (int i = 0; i < 4; ++i) {
            const int idx = i * 256 + tid;
            const int r = idx >> 3;
            const int p = (idx & 7) * 4;
            u16x4 a4, b4;
            if constexpr (A_F32) {
                const float* Af = (const float*)Av;
                f32x4 va = *(const f32x4*)(Af + (size_t)(row0 + r) * lda + k0 + p);
                a4[0] = f2bf(va[0]); a4[1] = f2bf(va[1]); a4[2] = f2bf(va[2]); a4[3] = f2bf(va[3]);
            } else {
                const u16* Ab = (const u16*)Av;
                a4 = *(const u16x4*)(Ab + (size_t)(row0 + r) * lda + k0 + p);
            }
            {
                f32x4 vb = *(const f32x4*)(B + (size_t)(col0 + r) * ldb + k0 + p);
                b4[0] = f2bf(vb[0]); b4[1] = f2bf(vb[1]); b4[2] = f2bf(vb[2]); b4[3] = f2bf(vb[3]);
            }
            *(u16x4*)&lA[r * 32 + p] = a4;
            *(u16x4*)&lB[r * 32 + p] = b4;
        }
        __syncthreads();

        bf16x8 af[4], bfv[4];
        #pragma unroll
        for (int m = 0; m < 4; ++m)
            af[m] = *(const bf16x8*)(lA + (wr + m * 16 + (lane & 15)) * 32 + (lane >> 4) * 8);
        #pragma unroll
        for (int n = 0; n < 4; ++n)
            bfv[n] = *(const bf16x8*)(lB + (wc + n * 16 + (lane & 15)) * 32 + (lane >> 4) * 8);
        #pragma unroll
        for (int m = 0; m < 4; ++m)
            #pragma unroll
            for (int n = 0; n < 4; ++n)
                acc[m][n] = __builtin_amdgcn_mfma_f32_16x16x32_bf16(af[m], bfv[n], acc[m][n], 0, 0, 0);
        __syncthreads();
    }

    if constexpr (NORMK) {
        if (col0 >= 512 && col0 < 1024) {
            #pragma unroll
            for (int m = 0; m < 4; ++m)
                #pragma unroll
                for (int j = 0; j < 4; ++j) {
                    float ss = 0.f;
                    #pragma unroll
                    for (int n = 0; n < 4; ++n) ss += acc[m][n][j] * acc[m][n][j];
                    ss += __shfl_xor(ss, 1);
                    ss += __shfl_xor(ss, 2);
                    ss += __shfl_xor(ss, 4);
                    ss += __shfl_xor(ss, 8);
                    const float scl = 1.f / fmaxf(sqrtf(ss), 1e-12f);
                    #pragma unroll
                    for (int n = 0; n < 4; ++n) acc[m][n][j] *= scl;
                }
        }
    }

    #pragma unroll
    for (int m = 0; m < 4; ++m) {
        const int r = row0 + wr + m * 16 + ((lane >> 4) << 2);
        #pragma unroll
        for (int n = 0; n < 4; ++n) {
            const int c = col0 + wc + n * 16 + (lane & 15);
            const float bv = bias ? bias[c] : 0.f;
            #pragma unroll
            for (int j = 0; j < 4; ++j) {
                const float val = acc[m][n][j] + bv;
                if constexpr (C_F32) ((float*)Cv)[(size_t)(r + j) * ldc + c] = val;
                else                 ((u16*)Cv)[(size_t)(r + j) * ldc + c] = f2bf(val);
            }
        }
    }
}

// ---------------------------------------------------------------------------
// Local attention, online-softmax over two 128-key chunks.
// One block per (b,h,window); 512 threads = 8 waves, wave owns 16 q-rows.
// K in qkv is PRE-NORMALIZED (GEMM1 epilogue). LDS 70.6KB -> 2 blocks/CU.
// Output written into the q-columns (exclusively owned by this block).
// ---------------------------------------------------------------------------
__global__ __launch_bounds__(512, 4) void attn_kernel(const u16* qkv, u16* o)
{
    constexpr int CC = 1536;
    constexpr int NTOK = 8192;
    constexpr int KP = 72;    // kn pitch (u16): 144B rows, bank-even
    constexpr int VP = 136;   // vT pitch: 272B rows
    constexpr int PP = 136;   // P pitch
    __shared__ u16 kn[128 * KP];   // K chunk [key][d]      18.4 KB
    __shared__ u16 vT[64 * VP];    // V chunk transposed    17.4 KB
    __shared__ u16 Pl[128 * PP];   // probs [row][key]      34.8 KB

    const int tid  = threadIdx.x;
    const int lane = tid & 63;
    const int wave = tid >> 6;
    const int cl = lane & 15;
    const int gr = lane >> 4;

    // XCD chunked swizzle (2048 % 8 == 0)
    int blk = blockIdx.x;
    blk = (blk & 7) * (gridDim.x >> 3) + (blk >> 3);

    const int iw  = blk & 63;
    const int h   = (blk >> 6) & 7;
    const int b   = blk >> 9;

    const int tq0 = iw * 128;
    const size_t rowbase = (size_t)b * NTOK;
    const u16* qbase = qkv + rowbase * CC + h * 64;
    const u16* kbase = qbase + 512;
    const u16* vbase = qbase + 1024;

    // ---- Q fragments (wave reads only its own 16 rows) ----
    const int wrow = wave * 16;
    bf16x8 qf[2];
    #pragma unroll
    for (int kk = 0; kk < 2; ++kk)
        qf[kk] = *(const bf16x8*)(qbase + (size_t)(tq0 + wrow + cl) * CC + kk * 32 + gr * 8);

    f32x4 oacc[4] = {};
    float m_run[4] = {-3.0e38f, -3.0e38f, -3.0e38f, -3.0e38f};
    float l_run[4] = {0.f, 0.f, 0.f, 0.f};

    for (int c = 0; c < 2; ++c) {
        const int tkc = tq0 - 128 + c * 128;   // token of local key 0 (block-uniform sign)

        // ---- stage K chunk (pure copy, pre-normalized) ----
        #pragma unroll
        for (int p = 0; p < 2; ++p) {
            const int id = tid + p * 512;      // 1024 chunks of 8
            const int row = id >> 3, dc = id & 7;
            u16x8 v8 = {};
            if (tkc >= 0) v8 = *(const u16x8*)(kbase + (size_t)(tkc + row) * CC + dc * 8);
            *(u16x8*)&kn[row * KP + dc * 8] = v8;
        }
        // ---- stage V chunk transposed (16B loads + scalar ds scatter) ----
        #pragma unroll
        for (int p = 0; p < 2; ++p) {
            const int id = tid + p * 512;
            const int key = id & 127, dc = id >> 7;   // dc 0..7
            u16x8 v8 = {};
            if (tkc >= 0) v8 = *(const u16x8*)(vbase + (size_t)(tkc + key) * CC + dc * 8);
            #pragma unroll
            for (int e = 0; e < 8; ++e) vT[(dc * 8 + e) * VP + key] = v8[e];
        }
        __syncthreads();

        // ---- S = Q @ Kn^T (16 rows x 128 keys) ----
        f32x4 s[8] = {};
        #pragma unroll
        for (int n = 0; n < 8; ++n)
            #pragma unroll
            for (int kk = 0; kk < 2; ++kk) {
                const bf16x8 kf = *(const bf16x8*)&kn[(n * 16 + cl) * KP + kk * 32 + gr * 8];
                s[n] = __builtin_amdgcn_mfma_f32_16x16x32_bf16(qf[kk], kf, s[n], 0, 0, 0);
            }

        // ---- mask + online softmax ----
        float pmax[4] = {-3.0e38f, -3.0e38f, -3.0e38f, -3.0e38f};
        #pragma unroll
        for (int n = 0; n < 8; ++n) {
            const int tkk = tkc + n * 16 + cl;
            const bool pad = tkk < 0;
            #pragma unroll
            for (int j = 0; j < 4; ++j) {
                const int tq = tq0 + wrow + gr * 4 + j;
                float sv = s[n][j] * 0.125f;            // D^-0.5
                const int rel = tkk - tq;
                sv = (rel == 0) ? -5.0e4f : sv;          // shared_qk self mask
                sv = (rel > 0 || pad) ? -6.0e4f : sv;    // causal / pad
                s[n][j] = sv;
                pmax[j] = fmaxf(pmax[j], sv);
            }
        }
        float cold[4];
        #pragma unroll
        for (int j = 0; j < 4; ++j) {
            pmax[j] = fmaxf(pmax[j], __shfl_xor(pmax[j], 1));
            pmax[j] = fmaxf(pmax[j], __shfl_xor(pmax[j], 2));
            pmax[j] = fmaxf(pmax[j], __shfl_xor(pmax[j], 4));
            pmax[j] = fmaxf(pmax[j], __shfl_xor(pmax[j], 8));
            const float mn = fmaxf(m_run[j], pmax[j]);
            cold[j] = __expf(m_run[j] - mn);
            m_run[j] = mn;
            l_run[j] *= cold[j];
        }
        #pragma unroll
        for (int n = 0; n < 8; ++n)
            #pragma unroll
            for (int j = 0; j < 4; ++j) {
                const float p = __expf(s[n][j] - m_run[j]);
                s[n][j] = p;
                l_run[j] += p;
            }
        #pragma unroll
        for (int n = 0; n < 4; ++n) {
            f32x4 t = oacc[n];
            t[0] *= cold[0]; t[1] *= cold[1]; t[2] *= cold[2]; t[3] *= cold[3];
            oacc[n] = t;
        }
        // ---- write P (bf16) ----
        #pragma unroll
        for (int n = 0; n < 8; ++n)
            #pragma unroll
            for (int j = 0; j < 4; ++j)
                Pl[(wrow + gr * 4 + j) * PP + n * 16 + cl] = f2bf(s[n][j]);
        __syncthreads();

        // ---- O += P @ V ----
        #pragma unroll
        for (int kk = 0; kk < 4; ++kk) {
            const bf16x8 pa = *(const bf16x8*)&Pl[(wrow + cl) * PP + kk * 32 + gr * 8];
            #pragma unroll
            for (int n = 0; n < 4; ++n) {
                const bf16x8 vb = *(const bf16x8*)&vT[(n * 16 + cl) * VP + kk * 32 + gr * 8];
                oacc[n] = __builtin_amdgcn_mfma_f32_16x16x32_bf16(pa, vb, oacc[n], 0, 0, 0);
            }
        }
        __syncthreads();   // before restaging kn/vT/Pl next chunk
    }

    // ---- finalize: divide by row sums, write into q-columns ----
    float inv[4];
    #pragma unroll
    for (int j = 0; j < 4; ++j) {
        l_run[j] += __shfl_xor(l_run[j], 1);
        l_run[j] += __shfl_xor(l_run[j], 2);
        l_run[j] += __shfl_xor(l_run[j], 4);
        l_run[j] += __shfl_xor(l_run[j], 8);
        inv[j] = 1.f / l_run[j];
    }
    u16* obase = o + rowbase * CC + h * 64;
    const int r0 = tq0 + wrow + gr * 4;
    #pragma unroll
    for (int n = 0; n < 4; ++n) {
        const int d = n * 16 + cl;
        #pragma unroll
        for (int j = 0; j < 4; ++j)
            obase[(size_t)(r0 + j) * CC + d] = f2bf(oacc[n][j] * inv[j]);
    }
}

extern "C" void kernel_launch(void* const* d_in, const int* in_sizes, int n_in,
                              void* d_out, int out_size, void* d_ws, size_t ws_size,
                              hipStream_t stream)
{
    (void)in_sizes; (void)n_in; (void)out_size;
    const float* x      = (const float*)d_in[0];   // [4,8192,512] fp32
    const float* w_qkv  = (const float*)d_in[1];   // [1536,512]   fp32
    const float* w_proj = (const float*)d_in[2];   // [512,512]    fp32
    const float* b_proj = (const float*)d_in[3];   // [512]        fp32
    float* out = (float*)d_out;                    // [4,8192,512] fp32

    const int BN = 4 * 8192;                       // 32768 rows
    const size_t qkv_b = (size_t)BN * 1536 * 2;    // 96 MiB
    const size_t xb_b  = (size_t)BN * 512 * 2;     // 32 MiB
    const size_t wq_b  = (size_t)1536 * 512 * 2;
    const size_t wp_b  = (size_t)512 * 512 * 2;

    uint8_t* p = (uint8_t*)d_ws;
    u16* qkv = (u16*)p;

    if (ws_size >= qkv_b + xb_b + wq_b + wp_b) {
        u16* xb  = (u16*)(p + qkv_b);
        u16* wqb = (u16*)(p + qkv_b + xb_b);
        u16* wpb = (u16*)(p + qkv_b + xb_b + wq_b);
        cvt_f32_bf16<<<1024, 256, 0, stream>>>(x, xb, BN * 512);
        cvt_f32_bf16<<<96, 256, 0, stream>>>(w_qkv, wqb, 1536 * 512);
        cvt_f32_bf16<<<32, 256, 0, stream>>>(w_proj, wpb, 512 * 512);
        // qkv(bf16) = x @ w_qkv^T, K-section L2-normalized in epilogue
        gemm_bt_bf16<false, true><<<dim3(12, BN / 128), 256, 0, stream>>>(
            xb, 512, wqb, 512, nullptr, qkv, 1536, 512);
        attn_kernel<<<dim3(4 * 8 * 64), 512, 0, stream>>>(qkv, qkv);
        gemm_bt_bf16<true, false><<<dim3(4, BN / 128), 256, 0, stream>>>(
            qkv, 1536, wpb, 512, b_proj, out, 512, 512);
    } else {
        // fallback: fp32 register-staged path
        gemm_bt_f32<true, false, true><<<dim3(12, BN / 128), 256, 0, stream>>>(
            x, 512, w_qkv, 512, nullptr, qkv, 1536, 512);
        attn_kernel<<<dim3(4 * 8 * 64), 512, 0, stream>>>(qkv, qkv);
        gemm_bt_f32<false, true, false><<<dim3(4, BN / 128), 256, 0, stream>>>(
            qkv, 1536, w_proj, 512, b_proj, out, 512, 512);
    }
}

// Round 5
// 186.351 us; speedup vs baseline: 1.5311x; 1.0779x over previous
//
#include <hip/hip_runtime.h>
#include <stdint.h>

typedef uint16_t u16;
typedef __bf16 bf16x8 __attribute__((ext_vector_type(8)));
typedef float f32x4 __attribute__((ext_vector_type(4)));
typedef uint16_t u16x4 __attribute__((ext_vector_type(4)));
typedef uint16_t u16x8 __attribute__((ext_vector_type(8)));

typedef __attribute__((address_space(1))) void as1_void;
typedef __attribute__((address_space(3))) void as3_void;

__device__ __forceinline__ float bf2f(u16 b) {
    union { uint32_t u; float f; } v; v.u = ((uint32_t)b) << 16; return v.f;
}
__device__ __forceinline__ u16 f2bf(float f) {
    union { float f; uint32_t u; } v; v.f = f;
    uint32_t u = v.u;
    u += 0x7fffu + ((u >> 16) & 1u);   // RNE
    return (u16)(u >> 16);
}
__device__ __forceinline__ void gload_lds16(const u16* g, u16* l) {
    __builtin_amdgcn_global_load_lds((as1_void*)g, (as3_void*)l, 16, 0, 0);
}

// ---------------------------------------------------------------------------
// Fused fp32->bf16 convert of x, w_qkv, w_proj in one launch.
// Segments: blocks [0,1024)=x(16.78M), [1024,1072)=w_qkv(786k), [1072,1088)=w_proj(262k).
// Every segment: 64 elems/thread = 8 chunks of 8.
// ---------------------------------------------------------------------------
__global__ __launch_bounds__(256) void cvt3(
    const float* __restrict__ x,  u16* __restrict__ xb,
    const float* __restrict__ wq, u16* __restrict__ wqb,
    const float* __restrict__ wp, u16* __restrict__ wpb)
{
    const float* src; u16* dst; int base, nb;
    const int b = blockIdx.x;
    if (b < 1024)      { src = x;  dst = xb;  base = b;        nb = 1024; }
    else if (b < 1072) { src = wq; dst = wqb; base = b - 1024; nb = 48;   }
    else               { src = wp; dst = wpb; base = b - 1072; nb = 16;   }
    size_t i = ((size_t)base * 256 + threadIdx.x) * 8;
    const size_t stride = (size_t)nb * 256 * 8;
    #pragma unroll
    for (int it = 0; it < 8; ++it, i += stride) {
        f32x4 a = *(const f32x4*)(src + i);
        f32x4 c = *(const f32x4*)(src + i + 4);
        u16x8 o;
        o[0] = f2bf(a[0]); o[1] = f2bf(a[1]); o[2] = f2bf(a[2]); o[3] = f2bf(a[3]);
        o[4] = f2bf(c[0]); o[5] = f2bf(c[1]); o[6] = f2bf(c[2]); o[7] = f2bf(c[3]);
        *(u16x8*)(dst + i) = o;
    }
}

// ---------------------------------------------------------------------------
// 256x256-tile bf16 GEMM, BK=64, 8 waves (2M x 4N), depth-2 counted-vmcnt
// pipeline (T3/T4), rotation LDS swizzle (conflict-free frag reads), raw
// s_barrier, setprio around MFMA (T5), XCD chunked swizzle (T1).
// C[M,N] = A[M,K] @ B[N,K]^T (+bias). K = NT*64.
// Rotation swizzle: 16B chunk of (row, chunk) stored at slot (chunk+row)&7;
// global_load_lds writes linearly, so the SOURCE address is inverse-permuted
// (rule #21) and ds_reads use the permuted slot.
// ---------------------------------------------------------------------------
template<int NT, bool C_F32, bool NORMK>
__global__ __launch_bounds__(512) void gemm256(
    const u16* __restrict__ A, int lda,
    const u16* __restrict__ B, int ldb,
    const float* __restrict__ bias,
    void* __restrict__ Cv, int ldc)
{
    __shared__ u16 lA[2][256 * 64];   // 64 KB
    __shared__ u16 lB[2][256 * 64];   // 64 KB

    const int tid  = threadIdx.x;
    const int lane = tid & 63;
    const int wave = tid >> 6;
    const int wm = wave >> 2;          // 0..1  (M half)
    const int wn = wave & 3;           // 0..3  (N quarter)
    const int cl = lane & 15;
    const int gr = lane >> 4;

    // T1: XCD chunked swizzle (grid sizes here always % 8 == 0)
    int fid = blockIdx.y * gridDim.x + blockIdx.x;
    const int nwg = gridDim.x * gridDim.y;
    fid = (fid & 7) * (nwg >> 3) + (fid >> 3);
    const int row0 = (fid / gridDim.x) * 256;
    const int col0 = (fid % gridDim.x) * 256;

    // staging constants: lane covers (srow, stored slot lane&7) of an 8-row group;
    // source chunk = (slot - row) & 7  (rotation inverse; Rg % 8 == 0)
    const int srow   = lane >> 3;
    const int schunk = ((lane & 7) - srow) & 7;

    f32x4 acc[8][4] = {};

    auto STAGE = [&](int t, int d) {
        const int k0 = t * 64;
        #pragma unroll
        for (int i = 0; i < 4; ++i) {
            const int Rg = wave * 32 + i * 8;            // 8-row group
            gload_lds16(A + (size_t)(row0 + Rg + srow) * lda + k0 + schunk * 8,
                        &lA[d][Rg * 64]);
            gload_lds16(B + (size_t)(col0 + Rg + srow) * ldb + k0 + schunk * 8,
                        &lB[d][Rg * 64]);
        }
    };

    auto COMPUTE = [&](int d) {
        const u16* la = lA[d];
        const u16* lb = lB[d];
        bf16x8 bfrag[2][4];
        #pragma unroll
        for (int kk = 0; kk < 2; ++kk)
            #pragma unroll
            for (int n = 0; n < 4; ++n) {
                const int rb = wn * 64 + n * 16 + cl;
                bfrag[kk][n] = *(const bf16x8*)(lb + rb * 64 + (((kk * 4 + gr + rb) & 7) * 8));
            }
        __builtin_amdgcn_s_setprio(1);
        #pragma unroll
        for (int m = 0; m < 8; ++m) {
            const int ra = wm * 128 + m * 16 + cl;
            const bf16x8 a0 = *(const bf16x8*)(la + ra * 64 + (((gr + ra) & 7) * 8));
            const bf16x8 a1 = *(const bf16x8*)(la + ra * 64 + (((4 + gr + ra) & 7) * 8));
            #pragma unroll
            for (int n = 0; n < 4; ++n)
                acc[m][n] = __builtin_amdgcn_mfma_f32_16x16x32_bf16(a0, bfrag[0][n], acc[m][n], 0, 0, 0);
            #pragma unroll
            for (int n = 0; n < 4; ++n)
                acc[m][n] = __builtin_amdgcn_mfma_f32_16x16x32_bf16(a1, bfrag[1][n], acc[m][n], 0, 0, 0);
        }
        __builtin_amdgcn_s_setprio(0);
    };

    STAGE(0, 0);                        //  8 loads in flight
    STAGE(1, 1);                        // 16 in flight
    #pragma unroll
    for (int t = 0; t < NT; ++t) {
        if (t < NT - 1) asm volatile("s_waitcnt vmcnt(8)" ::: "memory");  // tile t landed
        else            asm volatile("s_waitcnt vmcnt(0)" ::: "memory");
        __builtin_amdgcn_s_barrier();   // all waves' stages for tile t visible
        COMPUTE(t & 1);
        __builtin_amdgcn_s_barrier();   // all waves done reading buf[t&1]
        if (t + 2 < NT) STAGE(t + 2, t & 1);   // 8 more loads
    }

    if constexpr (NORMK) {
        // wave's 64 cols = one head; L2-normalize rows of the k-section
        if (col0 >= 512 && col0 < 1024) {
            #pragma unroll
            for (int m = 0; m < 8; ++m)
                #pragma unroll
                for (int j = 0; j < 4; ++j) {
                    float ss = 0.f;
                    #pragma unroll
                    for (int n = 0; n < 4; ++n) ss += acc[m][n][j] * acc[m][n][j];
                    ss += __shfl_xor(ss, 1);
                    ss += __shfl_xor(ss, 2);
                    ss += __shfl_xor(ss, 4);
                    ss += __shfl_xor(ss, 8);
                    const float scl = 1.f / fmaxf(sqrtf(ss), 1e-12f);
                    #pragma unroll
                    for (int n = 0; n < 4; ++n) acc[m][n][j] *= scl;
                }
        }
    }

    #pragma unroll
    for (int m = 0; m < 8; ++m) {
        const int r = row0 + wm * 128 + m * 16 + gr * 4;
        #pragma unroll
        for (int n = 0; n < 4; ++n) {
            const int c = col0 + wn * 64 + n * 16 + cl;
            const float bv = bias ? bias[c] : 0.f;
            #pragma unroll
            for (int j = 0; j < 4; ++j) {
                const float val = acc[m][n][j] + bv;
                if constexpr (C_F32) ((float*)Cv)[(size_t)(r + j) * ldc + c] = val;
                else                 ((u16*)Cv)[(size_t)(r + j) * ldc + c] = f2bf(val);
            }
        }
    }
}

// ---------------------------------------------------------------------------
// fp32-input fallback GEMM (register staging + convert). Used only if ws too small.
// ---------------------------------------------------------------------------
template<bool A_F32, bool C_F32, bool NORMK>
__global__ __launch_bounds__(256) void gemm_bt_f32(
    const void* __restrict__ Av, int lda,
    const float* __restrict__ B, int ldb,
    const float* __restrict__ bias,
    void* __restrict__ Cv, int ldc,
    int K)
{
    __shared__ u16 lA[128 * 32];
    __shared__ u16 lB[128 * 32];

    const int tid  = threadIdx.x;
    const int lane = tid & 63;
    const int wave = tid >> 6;
    const int wr   = (wave >> 1) * 64;
    const int wc   = (wave & 1) * 64;
    const int row0 = blockIdx.y * 128;
    const int col0 = blockIdx.x * 128;

    f32x4 acc[4][4] = {};

    for (int k0 = 0; k0 < K; k0 += 32) {
        #pragma unroll
        for (int i = 0; i < 4; ++i) {
            const int idx = i * 256 + tid;
            const int r = idx >> 3;
            const int p = (idx & 7) * 4;
            u16x4 a4, b4;
            if constexpr (A_F32) {
                const float* Af = (const float*)Av;
                f32x4 va = *(const f32x4*)(Af + (size_t)(row0 + r) * lda + k0 + p);
                a4[0] = f2bf(va[0]); a4[1] = f2bf(va[1]); a4[2] = f2bf(va[2]); a4[3] = f2bf(va[3]);
            } else {
                const u16* Ab = (const u16*)Av;
                a4 = *(const u16x4*)(Ab + (size_t)(row0 + r) * lda + k0 + p);
            }
            {
                f32x4 vb = *(const f32x4*)(B + (size_t)(col0 + r) * ldb + k0 + p);
                b4[0] = f2bf(vb[0]); b4[1] = f2bf(vb[1]); b4[2] = f2bf(vb[2]); b4[3] = f2bf(vb[3]);
            }
            *(u16x4*)&lA[r * 32 + p] = a4;
            *(u16x4*)&lB[r * 32 + p] = b4;
        }
        __syncthreads();

        bf16x8 af[4], bfv[4];
        #pragma unroll
        for (int m = 0; m < 4; ++m)
            af[m] = *(const bf16x8*)(lA + (wr + m * 16 + (lane & 15)) * 32 + (lane >> 4) * 8);
        #pragma unroll
        for (int n = 0; n < 4; ++n)
            bfv[n] = *(const bf16x8*)(lB + (wc + n * 16 + (lane & 15)) * 32 + (lane >> 4) * 8);
        #pragma unroll
        for (int m = 0; m < 4; ++m)
            #pragma unroll
            for (int n = 0; n < 4; ++n)
                acc[m][n] = __builtin_amdgcn_mfma_f32_16x16x32_bf16(af[m], bfv[n], acc[m][n], 0, 0, 0);
        __syncthreads();
    }

    if constexpr (NORMK) {
        if (col0 >= 512 && col0 < 1024) {
            #pragma unroll
            for (int m = 0; m < 4; ++m)
                #pragma unroll
                for (int j = 0; j < 4; ++j) {
                    float ss = 0.f;
                    #pragma unroll
                    for (int n = 0; n < 4; ++n) ss += acc[m][n][j] * acc[m][n][j];
                    ss += __shfl_xor(ss, 1);
                    ss += __shfl_xor(ss, 2);
                    ss += __shfl_xor(ss, 4);
                    ss += __shfl_xor(ss, 8);
                    const float scl = 1.f / fmaxf(sqrtf(ss), 1e-12f);
                    #pragma unroll
                    for (int n = 0; n < 4; ++n) acc[m][n][j] *= scl;
                }
        }
    }

    #pragma unroll
    for (int m = 0; m < 4; ++m) {
        const int r = row0 + wr + m * 16 + ((lane >> 4) << 2);
        #pragma unroll
        for (int n = 0; n < 4; ++n) {
            const int c = col0 + wc + n * 16 + (lane & 15);
            const float bv = bias ? bias[c] : 0.f;
            #pragma unroll
            for (int j = 0; j < 4; ++j) {
                const float val = acc[m][n][j] + bv;
                if constexpr (C_F32) ((float*)Cv)[(size_t)(r + j) * ldc + c] = val;
                else                 ((u16*)Cv)[(size_t)(r + j) * ldc + c] = f2bf(val);
            }
        }
    }
}

// ---------------------------------------------------------------------------
// Local attention, online-softmax over two 128-key chunks.
// One block per (b,h,window); 512 threads = 8 waves, wave owns 16 q-rows.
// K in qkv is PRE-NORMALIZED (GEMM1 epilogue). LDS 70.6KB -> 2 blocks/CU.
// Output written into the q-columns (exclusively owned by this block).
// ---------------------------------------------------------------------------
__global__ __launch_bounds__(512, 4) void attn_kernel(const u16* qkv, u16* o)
{
    constexpr int CC = 1536;
    constexpr int NTOK = 8192;
    constexpr int KP = 72;
    constexpr int VP = 136;
    constexpr int PP = 136;
    __shared__ u16 kn[128 * KP];
    __shared__ u16 vT[64 * VP];
    __shared__ u16 Pl[128 * PP];

    const int tid  = threadIdx.x;
    const int lane = tid & 63;
    const int wave = tid >> 6;
    const int cl = lane & 15;
    const int gr = lane >> 4;

    int blk = blockIdx.x;
    blk = (blk & 7) * (gridDim.x >> 3) + (blk >> 3);

    const int iw  = blk & 63;
    const int h   = (blk >> 6) & 7;
    const int b   = blk >> 9;

    const int tq0 = iw * 128;
    const size_t rowbase = (size_t)b * NTOK;
    const u16* qbase = qkv + rowbase * CC + h * 64;
    const u16* kbase = qbase + 512;
    const u16* vbase = qbase + 1024;

    const int wrow = wave * 16;
    bf16x8 qf[2];
    #pragma unroll
    for (int kk = 0; kk < 2; ++kk)
        qf[kk] = *(const bf16x8*)(qbase + (size_t)(tq0 + wrow + cl) * CC + kk * 32 + gr * 8);

    f32x4 oacc[4] = {};
    float m_run[4] = {-3.0e38f, -3.0e38f, -3.0e38f, -3.0e38f};
    float l_run[4] = {0.f, 0.f, 0.f, 0.f};

    for (int c = 0; c < 2; ++c) {
        const int tkc = tq0 - 128 + c * 128;

        #pragma unroll
        for (int p = 0; p < 2; ++p) {
            const int id = tid + p * 512;
            const int row = id >> 3, dc = id & 7;
            u16x8 v8 = {};
            if (tkc >= 0) v8 = *(const u16x8*)(kbase + (size_t)(tkc + row) * CC + dc * 8);
            *(u16x8*)&kn[row * KP + dc * 8] = v8;
        }
        #pragma unroll
        for (int p = 0; p < 2; ++p) {
            const int id = tid + p * 512;
            const int key = id & 127, dc = id >> 7;
            u16x8 v8 = {};
            if (tkc >= 0) v8 = *(const u16x8*)(vbase + (size_t)(tkc + key) * CC + dc * 8);
            #pragma unroll
            for (int e = 0; e < 8; ++e) vT[(dc * 8 + e) * VP + key] = v8[e];
        }
        __syncthreads();

        f32x4 s[8] = {};
        #pragma unroll
        for (int n = 0; n < 8; ++n)
            #pragma unroll
            for (int kk = 0; kk < 2; ++kk) {
                const bf16x8 kf = *(const bf16x8*)&kn[(n * 16 + cl) * KP + kk * 32 + gr * 8];
                s[n] = __builtin_amdgcn_mfma_f32_16x16x32_bf16(qf[kk], kf, s[n], 0, 0, 0);
            }

        float pmax[4] = {-3.0e38f, -3.0e38f, -3.0e38f, -3.0e38f};
        #pragma unroll
        for (int n = 0; n < 8; ++n) {
            const int tkk = tkc + n * 16 + cl;
            const bool pad = tkk < 0;
            #pragma unroll
            for (int j = 0; j < 4; ++j) {
                const int tq = tq0 + wrow + gr * 4 + j;
                float sv = s[n][j] * 0.125f;
                const int rel = tkk - tq;
                sv = (rel == 0) ? -5.0e4f : sv;
                sv = (rel > 0 || pad) ? -6.0e4f : sv;
                s[n][j] = sv;
                pmax[j] = fmaxf(pmax[j], sv);
            }
        }
        float cold[4];
        #pragma unroll
        for (int j = 0; j < 4; ++j) {
            pmax[j] = fmaxf(pmax[j], __shfl_xor(pmax[j], 1));
            pmax[j] = fmaxf(pmax[j], __shfl_xor(pmax[j], 2));
            pmax[j] = fmaxf(pmax[j], __shfl_xor(pmax[j], 4));
            pmax[j] = fmaxf(pmax[j], __shfl_xor(pmax[j], 8));
            const float mn = fmaxf(m_run[j], pmax[j]);
            cold[j] = __expf(m_run[j] - mn);
            m_run[j] = mn;
            l_run[j] *= cold[j];
        }
        #pragma unroll
        for (int n = 0; n < 8; ++n)
            #pragma unroll
            for (int j = 0; j < 4; ++j) {
                const float p = __expf(s[n][j] - m_run[j]);
                s[n][j] = p;
                l_run[j] += p;
            }
        #pragma unroll
        for (int n = 0; n < 4; ++n) {
            f32x4 t = oacc[n];
            t[0] *= cold[0]; t[1] *= cold[1]; t[2] *= cold[2]; t[3] *= cold[3];
            oacc[n] = t;
        }
        #pragma unroll
        for (int n = 0; n < 8; ++n)
            #pragma unroll
            for (int j = 0; j < 4; ++j)
                Pl[(wrow + gr * 4 + j) * PP + n * 16 + cl] = f2bf(s[n][j]);
        __syncthreads();

        #pragma unroll
        for (int kk = 0; kk < 4; ++kk) {
            const bf16x8 pa = *(const bf16x8*)&Pl[(wrow + cl) * PP + kk * 32 + gr * 8];
            #pragma unroll
            for (int n = 0; n < 4; ++n) {
                const bf16x8 vb = *(const bf16x8*)&vT[(n * 16 + cl) * VP + kk * 32 + gr * 8];
                oacc[n] = __builtin_amdgcn_mfma_f32_16x16x32_bf16(pa, vb, oacc[n], 0, 0, 0);
            }
        }
        __syncthreads();
    }

    float inv[4];
    #pragma unroll
    for (int j = 0; j < 4; ++j) {
        l_run[j] += __shfl_xor(l_run[j], 1);
        l_run[j] += __shfl_xor(l_run[j], 2);
        l_run[j] += __shfl_xor(l_run[j], 4);
        l_run[j] += __shfl_xor(l_run[j], 8);
        inv[j] = 1.f / l_run[j];
    }
    u16* obase = o + rowbase * CC + h * 64;
    const int r0 = tq0 + wrow + gr * 4;
    #pragma unroll
    for (int n = 0; n < 4; ++n) {
        const int d = n * 16 + cl;
        #pragma unroll
        for (int j = 0; j < 4; ++j)
            obase[(size_t)(r0 + j) * CC + d] = f2bf(oacc[n][j] * inv[j]);
    }
}

extern "C" void kernel_launch(void* const* d_in, const int* in_sizes, int n_in,
                              void* d_out, int out_size, void* d_ws, size_t ws_size,
                              hipStream_t stream)
{
    (void)in_sizes; (void)n_in; (void)out_size;
    const float* x      = (const float*)d_in[0];   // [4,8192,512] fp32
    const float* w_qkv  = (const float*)d_in[1];   // [1536,512]   fp32
    const float* w_proj = (const float*)d_in[2];   // [512,512]    fp32
    const float* b_proj = (const float*)d_in[3];   // [512]        fp32
    float* out = (float*)d_out;                    // [4,8192,512] fp32

    const int BN = 4 * 8192;                       // 32768 rows
    const size_t qkv_b = (size_t)BN * 1536 * 2;    // 96 MiB
    const size_t xb_b  = (size_t)BN * 512 * 2;     // 32 MiB
    const size_t wq_b  = (size_t)1536 * 512 * 2;
    const size_t wp_b  = (size_t)512 * 512 * 2;

    uint8_t* p = (uint8_t*)d_ws;
    u16* qkv = (u16*)p;

    if (ws_size >= qkv_b + xb_b + wq_b + wp_b) {
        u16* xb  = (u16*)(p + qkv_b);
        u16* wqb = (u16*)(p + qkv_b + xb_b);
        u16* wpb = (u16*)(p + qkv_b + xb_b + wq_b);
        cvt3<<<1088, 256, 0, stream>>>(x, xb, w_qkv, wqb, w_proj, wpb);
        // qkv(bf16) = x @ w_qkv^T, K-section L2-normalized in epilogue
        gemm256<8, false, true><<<dim3(6, 128), 512, 0, stream>>>(
            xb, 512, wqb, 512, nullptr, qkv, 1536);
        attn_kernel<<<dim3(4 * 8 * 64), 512, 0, stream>>>(qkv, qkv);
        // out(fp32) = attnO @ w_proj^T + b_proj
        gemm256<8, true, false><<<dim3(2, 128), 512, 0, stream>>>(
            qkv, 1536, wpb, 512, b_proj, out, 512);
    } else {
        // fallback: fp32 register-staged path
        gemm_bt_f32<true, false, true><<<dim3(12, BN / 128), 256, 0, stream>>>(
            x, 512, w_qkv, 512, nullptr, qkv, 1536, 512);
        attn_kernel<<<dim3(4 * 8 * 64), 512, 0, stream>>>(qkv, qkv);
        gemm_bt_f32<false, true, false><<<dim3(4, BN / 128), 256, 0, stream>>>(
            qkv, 1536, w_proj, 512, b_proj, out, 512, 512);
    }
}